// Round 3
// baseline (862.335 us; speedup 1.0000x reference)
//
#include <hip/hip_runtime.h>

typedef unsigned short u16;
typedef unsigned int u32;

#define E_TOTAL 65536

// ws layout (floats): [0:768] per-graph stat sums (16 graphs x 48 slots),
//   slot s<16: sum s_out[ch]; s in [16,32): sum s_out[ch]^2; s in [32,40): sum |v_o|^2; s==40: count
// [768:1024] mu[g][ch]; [1024:1040] inv_rms_s[g]; [1040:1056] inv_rms_v[g]

__global__ void k_zero(float* __restrict__ ws) {
    const int i = threadIdx.x + blockIdx.x * blockDim.x;
    if (i < 1056) ws[i] = 0.0f;
}

// ---------------- Kernel 1: heavy per-edge conv ----------------
// 16 edges per block, 256 threads. Writes s_out(16)+v_out(24) f32 into out.
__global__ __launch_bounds__(256) void k_edge_heavy(
    const float* __restrict__ node_fea, const float* __restrict__ edge_attr,
    const int* __restrict__ edge_index, const int* __restrict__ xsp,
    const float* __restrict__ w_rh, const float* __restrict__ b_rh,
    const float* __restrict__ w_ro, const float* __restrict__ b_ro,
    const float* __restrict__ w_pre, const float* __restrict__ b_pre,
    const float* __restrict__ w_sc, const float* __restrict__ w_post_s,
    const float* __restrict__ b_post_s, const float* __restrict__ w_post_v,
    float* __restrict__ out)
{
    __shared__ __align__(16) float sh_h[64][16];      // h transposed [k][edge]
    __shared__ __align__(16) float sh_wt[16][260];    // w_all chunk tile (pad 260)
    __shared__ float sh_rbf[16][128];
    __shared__ float sh_sin[16][80];    // s_in * (1/sqrt80)
    __shared__ float sh_vl[16][3][32];  // v_in[c][i] * (1/sqrt32)
    __shared__ float sh_q[16][32];      // (v_in . Y1) * (1/sqrt96)
    __shared__ float sh_cr[16][3][32];  // cross(v_in,Y1)[c][i] * (1/sqrt64)
    __shared__ float sh_acc[16][56];    // [0:24]=s_conv, [24:32]=a2(vA), [32:56]=v(o,c)
    __shared__ float sh_es0[16][16];
    __shared__ float sh_sc[16][16];
    __shared__ float sh_y1[16][4];

    const int tid = threadIdx.x;
    const int ed = tid >> 4, l16 = tid & 15;
    const int e = blockIdx.x * 16 + ed;

    const int ni = edge_index[e];
    const int nj = edge_index[E_TOTAL + e];
    const float4 ea = *(const float4*)(edge_attr + 4*e);
    const float d  = ea.x;
    const float vx = ea.y, vy = ea.z, vz = ea.w;
    const float invn = 1.0f / (sqrtf(vx*vx + vy*vy + vz*vz) + 1e-12f);
    const float Y0 = 1.7320508075688772f * vx * invn;
    const float Y1 = 1.7320508075688772f * vy * invn;
    const float Y2 = 1.7320508075688772f * vz * invn;
    if (l16 == 0) { sh_y1[ed][0] = Y0; sh_y1[ed][1] = Y1; sh_y1[ed][2] = Y2; }

    const float C128 = -0.5f * (127.0f/6.0f) * (127.0f/6.0f);
    const float S128 = 6.0f/127.0f;
    #pragma unroll
    for (int r = 0; r < 8; ++r) {
        const int b = l16*8 + r;
        const float t = d - S128 * (float)b;
        sh_rbf[ed][b] = expf(C128 * t * t);
    }
    {
        const float t = d - 0.4f * (float)l16;
        sh_es0[ed][l16] = expf(-3.125f * t * t);
    }

    const float rs80 = 0.11180339887498949f;   // 1/sqrt(80)
    const float rs32 = 0.17677669529663689f;   // 1/sqrt(32)
    {
        const float* fi = node_fea + (size_t)ni * 80;
        const float* fj = node_fea + (size_t)nj * 80;
        sh_sin[ed][2*l16+0]    = fi[2*l16+0] * rs80;
        sh_sin[ed][2*l16+1]    = fi[2*l16+1] * rs80;
        sh_sin[ed][32+2*l16+0] = fj[2*l16+0] * rs80;
        sh_sin[ed][32+2*l16+1] = fj[2*l16+1] * rs80;
        #pragma unroll
        for (int c = 0; c < 3; ++c) {
            sh_vl[ed][c][l16]      = fi[32 + 3*l16 + c] * rs32;
            sh_vl[ed][c][16 + l16] = fj[32 + 3*l16 + c] * rs32;
        }
    }
    for (int s = tid; s < 16*56; s += 256) (&sh_acc[0][0])[s] = 0.0f;
    __syncthreads();

    // edge_s (scaled, into sin[64:80]) and sc
    {
        const int o = l16;
        float es = b_pre[o];
        float sc = 0.0f;
        const int p = 4*xsp[ni] + xsp[nj];
        #pragma unroll
        for (int i = 0; i < 16; ++i) {
            const float g = sh_es0[ed][i];
            es += g * w_pre[i*16 + o];
            sc += g * w_sc[(i*16 + p)*16 + o];
        }
        sh_sin[ed][64 + o] = es * rs80;
        sh_sc[ed][o] = sc * 0.0625f;            // / sqrt(16*16)
    }
    // q and cross (rescaled from sh_vl: *sqrt(32/96), *sqrt(32/64))
    #pragma unroll
    for (int rr = 0; rr < 2; ++rr) {
        const int i = l16 + 16*rr;
        const float a0 = sh_vl[ed][0][i];
        const float a1 = sh_vl[ed][1][i];
        const float a2 = sh_vl[ed][2][i];
        sh_q[ed][i] = (a0*Y0 + a1*Y1 + a2*Y2) * 0.57735026918962573f;
        sh_cr[ed][0][i] = (a1*Y2 - a2*Y1) * 0.70710678118654746f;
        sh_cr[ed][1][i] = (a2*Y0 - a0*Y2) * 0.70710678118654746f;
        sh_cr[ed][2][i] = (a0*Y1 - a1*Y0) * 0.70710678118654746f;
    }
    // h = silu(rbf @ w_rh + b_rh)
    #pragma unroll
    for (int r = 0; r < 4; ++r) {
        const int k = l16 + 16*r;
        float a = b_rh[k];
        for (int b = 0; b < 128; ++b) a += sh_rbf[ed][b] * w_rh[b*64 + k];
        sh_h[k][ed] = a / (1.0f + expf(-a));
    }
    __syncthreads();

    // -------- main loop: w_all in 15 chunks of 256 cols --------
    const int cq = tid & 63;   // column quad (4 cols)
    const int eq = tid >> 6;   // edge quad  (4 edges)

    for (int ch = 0; ch < 15; ++ch) {
        const int coff = ch * 256;
        float4 wv[4];
        {
            const int g0 = coff + cq*4;
            const float4 bv = *(const float4*)(b_ro + g0);
            #pragma unroll
            for (int ee = 0; ee < 4; ++ee) wv[ee] = bv;
            const float* wp = w_ro + g0;
            #pragma unroll 8
            for (int k = 0; k < 64; ++k) {
                const float4 wu = *(const float4*)(wp + (size_t)k * 3840);
                const float w0 = wu.x, w1 = wu.y, w2 = wu.z, w3 = wu.w;
                const float4 hv = *(const float4*)(&sh_h[k][eq*4]);
                wv[0].x += hv.x*w0; wv[0].y += hv.x*w1; wv[0].z += hv.x*w2; wv[0].w += hv.x*w3;
                wv[1].x += hv.y*w0; wv[1].y += hv.y*w1; wv[1].z += hv.y*w2; wv[1].w += hv.y*w3;
                wv[2].x += hv.z*w0; wv[2].y += hv.z*w1; wv[2].z += hv.z*w2; wv[2].w += hv.z*w3;
                wv[3].x += hv.w*w0; wv[3].y += hv.w*w1; wv[3].z += hv.w*w2; wv[3].w += hv.w*w3;
            }
        }
        __syncthreads();   // previous chunk's owners done with sh_wt
        #pragma unroll
        for (int ee = 0; ee < 4; ++ee)
            *(float4*)(&sh_wt[eq*4 + ee][cq*4]) = wv[ee];
        __syncthreads();

        if (ch <= 7) {  // w1: 80x24 (cols 0..1920), -> s_conv
            const int hi = (ch == 7) ? 1920 : (coff + 256);
            for (int idx = tid; idx < 384; idx += 256) {
                const int eo = idx / 24, o = idx % 24;
                const int i0 = (coff > o) ? (coff - o + 23) / 24 : 0;
                int i1 = (hi - o + 23) / 24; if (i1 > 80) i1 = 80;
                float a = 0.0f;
                for (int i = i0; i < i1; ++i)
                    a += sh_sin[eo][i] * sh_wt[eo][i*24 + o - coff];
                sh_acc[eo][o] += a;
            }
        }
        if (ch == 7) {  // w2 rows 0..15 (cols 1920..2047): tile col = 128 + i*8 + o
            for (int idx = tid; idx < 128; idx += 256) {
                const int eo = idx >> 3, o = idx & 7;
                float a = 0.0f;
                #pragma unroll
                for (int i = 0; i < 16; ++i)
                    a += sh_sin[eo][i] * sh_wt[eo][128 + i*8 + o];
                sh_acc[eo][24 + o] += a;
            }
        }
        if (ch == 8 || ch == 9) {  // w2 rows 16..47 / 48..79
            const int ib = (ch == 8) ? 16 : 48;
            for (int idx = tid; idx < 128; idx += 256) {
                const int eo = idx >> 3, o = idx & 7;
                float a = 0.0f;
                #pragma unroll
                for (int i2 = 0; i2 < 32; ++i2)
                    a += sh_sin[eo][ib + i2] * sh_wt[eo][i2*8 + o];
                sh_acc[eo][24 + o] += a;
            }
        }
        if (ch == 10) {  // w3: 32x8 (cols 2560..2815), left = v_in[:,c]
            for (int idx = tid; idx < 384; idx += 256) {
                const int eo = idx / 24, rem = idx % 24;
                const int o = rem / 3, cc = rem % 3;
                float a = 0.0f;
                #pragma unroll
                for (int i = 0; i < 32; ++i)
                    a += sh_vl[eo][cc][i] * sh_wt[eo][i*8 + o];
                sh_acc[eo][32 + o*3 + cc] += a;
            }
        }
        if (ch >= 11 && ch <= 13) {  // w4: 32x24 (cols 2816..3583), left = q, -> s_conv
            const int rel = coff - 2816;
            for (int idx = tid; idx < 384; idx += 256) {
                const int eo = idx / 24, o = idx % 24;
                const int i0 = (rel > o) ? (rel - o + 23) / 24 : 0;
                int i1 = (rel + 256 - o + 23) / 24; if (i1 > 32) i1 = 32;
                float a = 0.0f;
                for (int i = i0; i < i1; ++i)
                    a += sh_q[eo][i] * sh_wt[eo][i*24 + o - rel];
                sh_acc[eo][o] += a;
            }
        }
        if (ch == 14) {  // w5: 32x8 (cols 3584..3839), left = cross
            for (int idx = tid; idx < 384; idx += 256) {
                const int eo = idx / 24, rem = idx % 24;
                const int o = rem / 3, cc = rem % 3;
                float a = 0.0f;
                #pragma unroll
                for (int i = 0; i < 32; ++i)
                    a += sh_cr[eo][cc][i] * sh_wt[eo][i*8 + o];
                sh_acc[eo][32 + o*3 + cc] += a;
            }
        }
    }
    __syncthreads();

    // -------- epilogue: gate + post projections, f32 store into out --------
    {
        const int o = l16;
        float a = b_post_s[o] + sh_sc[ed][o];
        #pragma unroll
        for (int i = 0; i < 16; ++i) {
            const float sv = sh_acc[ed][i];
            a += (sv / (1.0f + expf(-sv))) * w_post_s[i*16 + o];
        }
        out[(size_t)e*40 + o] = a;
    }
    if (l16 < 8) {
        const int o = l16;
        const float Ya = sh_y1[ed][0], Yb = sh_y1[ed][1], Yc = sh_y1[ed][2];
        float r0 = 0.0f, r1 = 0.0f, r2 = 0.0f;
        #pragma unroll
        for (int i = 0; i < 8; ++i) {
            const float g  = 1.0f / (1.0f + expf(-sh_acc[ed][16 + i]));
            const float a2 = sh_acc[ed][24 + i];
            const float w  = w_post_v[i*8 + o];
            r0 += (a2*Ya + sh_acc[ed][32 + i*3 + 0]) * g * w;
            r1 += (a2*Yb + sh_acc[ed][32 + i*3 + 1]) * g * w;
            r2 += (a2*Yc + sh_acc[ed][32 + i*3 + 2]) * g * w;
        }
        out[(size_t)e*40 + 16 + o*3 + 0] = r0;
        out[(size_t)e*40 + 16 + o*3 + 1] = r1;
        out[(size_t)e*40 + 16 + o*3 + 2] = r2;
    }
}

// ---------------- Kernel 2a: per-block segment-stat partials + atomicAdd ----------------
__global__ __launch_bounds__(256) void k_stats_partial(
    const float* __restrict__ sv, const int* __restrict__ edge_index,
    const int* __restrict__ batch, float* __restrict__ ws)
{
    __shared__ float sh_ed[256][40];
    __shared__ int   sh_eb[256];
    const int tid = threadIdx.x;
    const int e = blockIdx.x * 256 + tid;
    sh_eb[tid] = batch[edge_index[e]];
    const float* p = sv + (size_t)e * 40;
    #pragma unroll
    for (int j = 0; j < 40; ++j) sh_ed[tid][j] = p[j];
    __syncthreads();

    for (int slot = tid; slot < 768; slot += 256) {
        const int g = slot / 48, s = slot % 48;
        float acc = 0.0f;
        if (s < 16) {
            for (int k = 0; k < 256; ++k) {
                const float m = (sh_eb[k] == g) ? 1.0f : 0.0f;
                acc += m * sh_ed[k][s];
            }
        } else if (s < 32) {
            for (int k = 0; k < 256; ++k) {
                const float m = (sh_eb[k] == g) ? 1.0f : 0.0f;
                const float v = sh_ed[k][s - 16];
                acc += m * v * v;
            }
        } else if (s < 40) {
            const int o3 = 16 + (s - 32) * 3;
            for (int k = 0; k < 256; ++k) {
                const float m = (sh_eb[k] == g) ? 1.0f : 0.0f;
                const float v0 = sh_ed[k][o3], v1 = sh_ed[k][o3+1], v2 = sh_ed[k][o3+2];
                acc += m * (v0*v0 + v1*v1 + v2*v2);
            }
        } else if (s == 40) {
            for (int k = 0; k < 256; ++k) acc += (sh_eb[k] == g) ? 1.0f : 0.0f;
        }
        atomicAdd(&ws[slot], acc);
    }
}

// ---------------- Kernel 2b: finalize per-graph mu / inv_rms ----------------
__global__ __launch_bounds__(64) void k_stats_final(float* __restrict__ ws)
{
    const int tid = threadIdx.x;
    if (tid < 16) {
        const int g = tid;
        float cnt = ws[g*48 + 40]; if (cnt < 1.0f) cnt = 1.0f;
        const float ic = 1.0f / cnt;
        float vs = 0.0f;
        for (int chn = 0; chn < 16; ++chn) {
            const float mu = ws[g*48 + chn] * ic;
            ws[768 + g*16 + chn] = mu;
            vs += ws[g*48 + 16 + chn] * ic - mu * mu;
        }
        if (vs < 0.0f) vs = 0.0f;
        ws[1024 + g] = 1.0f / sqrtf(vs * (1.0f/16.0f) + 1e-5f);
        float vv = 0.0f;
        for (int o = 0; o < 8; ++o) vv += ws[g*48 + 32 + o];
        vv = vv * ic * (1.0f/3.0f) * (1.0f/8.0f);
        ws[1040 + g] = 1.0f / sqrtf(vv + 1e-5f);
    }
}

// ---------------- Kernel 4: LN + skip + edge projections, in place on out ----------------
__global__ __launch_bounds__(256) void k_edge_final(
    float* buf, const float* __restrict__ ws,
    const float* __restrict__ edge_attr, const int* __restrict__ edge_index,
    const int* __restrict__ batch,
    const float* __restrict__ ln_w_s, const float* __restrict__ ln_b_s,
    const float* __restrict__ ln_w_v, const float* __restrict__ w_skip,
    const float* __restrict__ w_edge_s, const float* __restrict__ b_edge_s,
    const float* __restrict__ w_edge_v)
{
    __shared__ float sh_mu[16][16];
    __shared__ float sh_is[16], sh_iv[16];
    __shared__ float sh_lws[16], sh_lbs[16], sh_lwv[8];
    __shared__ float sh_skip[16][16], sh_wes[16][16], sh_bes[16], sh_wev[8][8];
    const int tid = threadIdx.x;
    sh_mu[tid >> 4][tid & 15]   = ws[768 + tid];
    sh_skip[tid >> 4][tid & 15] = w_skip[tid];
    sh_wes[tid >> 4][tid & 15]  = w_edge_s[tid];
    if (tid < 16) {
        sh_is[tid]  = ws[1024 + tid];
        sh_iv[tid]  = ws[1040 + tid];
        sh_lws[tid] = ln_w_s[tid];
        sh_lbs[tid] = ln_b_s[tid];
        sh_bes[tid] = b_edge_s[tid];
    }
    if (tid < 8)  sh_lwv[tid] = ln_w_v[tid];
    if (tid < 64) sh_wev[tid >> 3][tid & 7] = w_edge_v[tid];
    __syncthreads();

    const int e = blockIdx.x * 256 + tid;
    const int g = batch[edge_index[e]];
    const float d = edge_attr[4*e];
    float es0[16];
    #pragma unroll
    for (int b = 0; b < 16; ++b) {
        const float t = d - 0.4f * (float)b;
        es0[b] = expf(-3.125f * t * t);
    }
    // read my 40 intermediates into registers BEFORE any store (same thread, in place)
    float p[40];
    float* pb = buf + (size_t)e * 40;
    #pragma unroll
    for (int j = 0; j < 40; ++j) p[j] = pb[j];

    const float is = sh_is[g];
    float sn[16];
    #pragma unroll
    for (int chn = 0; chn < 16; ++chn)
        sn[chn] = (p[chn] - sh_mu[g][chn]) * is * sh_lws[chn] + sh_lbs[chn];
    #pragma unroll
    for (int b = 0; b < 16; ++b) {
        const float g0 = es0[b];
        #pragma unroll
        for (int chn = 0; chn < 16; ++chn) sn[chn] += g0 * sh_skip[b][chn];
    }
    #pragma unroll
    for (int o = 0; o < 16; ++o) {
        float a = sh_bes[o];
        #pragma unroll
        for (int chn = 0; chn < 16; ++chn) a += sn[chn] * sh_wes[chn][o];
        pb[o] = a;
    }
    const float iv = sh_iv[g];
    float vn[8][3];
    #pragma unroll
    for (int i = 0; i < 8; ++i) {
        const float f = iv * sh_lwv[i];
        vn[i][0] = p[16 + i*3 + 0] * f;
        vn[i][1] = p[16 + i*3 + 1] * f;
        vn[i][2] = p[16 + i*3 + 2] * f;
    }
    #pragma unroll
    for (int o = 0; o < 8; ++o) {
        float r0 = 0.0f, r1 = 0.0f, r2 = 0.0f;
        #pragma unroll
        for (int i = 0; i < 8; ++i) {
            const float w = sh_wev[i][o];
            r0 += vn[i][0] * w; r1 += vn[i][1] * w; r2 += vn[i][2] * w;
        }
        pb[16 + o*3 + 0] = r0;
        pb[16 + o*3 + 1] = r1;
        pb[16 + o*3 + 2] = r2;
    }
}

extern "C" void kernel_launch(void* const* d_in, const int* in_sizes, int n_in,
                              void* d_out, int out_size, void* d_ws, size_t ws_size,
                              hipStream_t stream)
{
    const float* node_fea  = (const float*)d_in[0];
    const float* edge_attr = (const float*)d_in[1];
    const int* edge_index  = (const int*)d_in[2];
    const int* xsp         = (const int*)d_in[3];
    const int* batch       = (const int*)d_in[4];
    const float* w_rh      = (const float*)d_in[5];
    const float* b_rh      = (const float*)d_in[6];
    const float* w_ro      = (const float*)d_in[7];
    const float* b_ro      = (const float*)d_in[8];
    const float* w_pre     = (const float*)d_in[9];
    const float* b_pre     = (const float*)d_in[10];
    const float* w_sc      = (const float*)d_in[11];
    const float* w_post_s  = (const float*)d_in[12];
    const float* b_post_s  = (const float*)d_in[13];
    const float* w_post_v  = (const float*)d_in[14];
    const float* ln_w_s    = (const float*)d_in[15];
    const float* ln_b_s    = (const float*)d_in[16];
    const float* ln_w_v    = (const float*)d_in[17];
    const float* w_skip    = (const float*)d_in[18];
    const float* w_edge_s  = (const float*)d_in[19];
    const float* b_edge_s  = (const float*)d_in[20];
    const float* w_edge_v  = (const float*)d_in[21];

    float* ws  = (float*)d_ws;          // only 1056 floats used (~4.2 KB)
    float* out = (float*)d_out;

    k_zero<<<2, 1024, 0, stream>>>(ws);
    k_edge_heavy<<<4096, 256, 0, stream>>>(node_fea, edge_attr, edge_index, xsp,
        w_rh, b_rh, w_ro, b_ro, w_pre, b_pre, w_sc, w_post_s, b_post_s, w_post_v,
        out);
    k_stats_partial<<<256, 256, 0, stream>>>(out, edge_index, batch, ws);
    k_stats_final<<<1, 64, 0, stream>>>(ws);
    k_edge_final<<<256, 256, 0, stream>>>(out, ws, edge_attr, edge_index,
        batch, ln_w_s, ln_b_s, ln_w_v, w_skip, w_edge_s, b_edge_s, w_edge_v);
}

// Round 7
// 604.470 us; speedup vs baseline: 1.4266x; 1.4266x over previous
//
#include <hip/hip_runtime.h>

typedef unsigned short u16;
typedef unsigned int u32;
typedef __attribute__((ext_vector_type(8))) short short8;
typedef __attribute__((ext_vector_type(4))) float floatx4;

#define E_TOTAL 65536

__device__ __forceinline__ u16 f2bf(float f) {
    union { float f; u32 i; } c; c.f = f;
    const u32 u = c.i;
    const u32 r = (u + 0x7fffu + ((u >> 16) & 1u)) >> 16;   // RNE, finite inputs
    return (u16)r;
}
__device__ __forceinline__ float bfu2f(u16 u) {
    union { u32 i; float f; } c; c.i = ((u32)u) << 16; return c.f;
}

// ws layout (floats): [0:768] per-graph stat sums, [768:1024] mu, [1024:1040] irs,
// [1040:1056] irv; ints [1056:1088] = binv (B-slot -> logical k pairing map)

__global__ void k_zero(float* __restrict__ ws) {
    const int i = threadIdx.x + blockIdx.x * blockDim.x;
    if (i < 1056) ws[i] = 0.0f;
}

// ---------------- Probe: measure A-slot <-> B-slot k-pairing of mfma_16x16x32_bf16 ----
__global__ __launch_bounds__(64) void k_probe(int* __restrict__ binv) {
    const int lane = threadIdx.x;
    const int q = lane >> 4;
    if (lane < 32) binv[lane] = lane;    // default identity (safety)
    short8 bfr;
    #pragma unroll
    for (int j = 0; j < 8; ++j) bfr[j] = (short)f2bf((float)(q*8 + j + 1));
    #pragma unroll
    for (int s = 0; s < 32; ++s) {
        const int qa = s >> 3, ja = s & 7;
        short8 afr = {0,0,0,0,0,0,0,0};
        if (q == qa) afr[ja] = (short)f2bf(1.0f);
        floatx4 dc = {0.0f, 0.0f, 0.0f, 0.0f};
        dc = __builtin_amdgcn_mfma_f32_16x16x32_bf16(afr, bfr, dc, 0, 0, 0);
        if (lane == 0) {
            const int sB = (int)(dc[0] + 0.5f) - 1;   // B-slot paired with A-slot s
            if (sB >= 0 && sB < 32) binv[sB] = s;     // logical k of that B-slot
        }
    }
}

// ---------------- Kernel 1: heavy per-edge conv (split-precision MFMA) ----------------
__global__ __launch_bounds__(256) void k_edge_heavy(
    const float* __restrict__ node_fea, const float* __restrict__ edge_attr,
    const int* __restrict__ edge_index, const int* __restrict__ xsp,
    const float* __restrict__ w_rh, const float* __restrict__ b_rh,
    const float* __restrict__ w_ro, const float* __restrict__ b_ro,
    const float* __restrict__ w_pre, const float* __restrict__ b_pre,
    const float* __restrict__ w_sc, const float* __restrict__ w_post_s,
    const float* __restrict__ b_post_s, const float* __restrict__ w_post_v,
    const int* __restrict__ binv,
    float* __restrict__ out)
{
    __shared__ __align__(16) u16 a_rbf[2][16 * 128]; // [hi|lo] A-frag: (m,k) at ((k>>3)*16+m)*8+(k&7)
    __shared__ __align__(16) u16 a_h[2][16 * 64];    // [hi|lo] same convention, K=64
    __shared__ __align__(16) float sh_wt[16][260];   // w_all chunk tile (pad 260)
    __shared__ float sh_sin[16][80];    // s_in * (1/sqrt80)
    __shared__ float sh_vl[16][3][32];  // v_in[c][i] * (1/sqrt32)
    __shared__ float sh_q[16][32];      // (v_in . Y1) * (1/sqrt96)
    __shared__ float sh_cr[16][3][32];  // cross(v_in,Y1)[c][i] * (1/sqrt64)
    __shared__ float sh_acc[16][56];    // [0:24]=s_conv, [24:32]=a2(vA), [32:56]=v(o,c)
    __shared__ float sh_es0[16][16];
    __shared__ float sh_sc[16][16];
    __shared__ float sh_y1[16][4];
    __shared__ int   sh_kmap[32];

    const int tid = threadIdx.x;
    const int ed = tid >> 4, l16 = tid & 15;
    const int lane = tid & 63, w = tid >> 6;
    const int quad = lane >> 4, l15 = lane & 15;
    const int e = blockIdx.x * 16 + ed;

    if (tid < 32) sh_kmap[tid] = binv[tid];

    const int ni = edge_index[e];
    const int nj = edge_index[E_TOTAL + e];
    const float4 ea = *(const float4*)(edge_attr + 4*e);
    const float d  = ea.x;
    const float vx = ea.y, vy = ea.z, vz = ea.w;
    const float invn = 1.0f / (sqrtf(vx*vx + vy*vy + vz*vz) + 1e-12f);
    const float Y0 = 1.7320508075688772f * vx * invn;
    const float Y1 = 1.7320508075688772f * vy * invn;
    const float Y2 = 1.7320508075688772f * vz * invn;
    if (l16 == 0) { sh_y1[ed][0] = Y0; sh_y1[ed][1] = Y1; sh_y1[ed][2] = Y2; }

    // rbf -> hi/lo bf16 A-fragments
    const float C128 = -0.5f * (127.0f/6.0f) * (127.0f/6.0f);
    const float S128 = 6.0f/127.0f;
    {
        short8 thi, tlo;
        #pragma unroll
        for (int r = 0; r < 8; ++r) {
            const int b = l16*8 + r;
            const float t = d - S128 * (float)b;
            const float x = expf(C128 * t * t);
            const u16 hi = f2bf(x);
            thi[r] = (short)hi;
            tlo[r] = (short)f2bf(x - bfu2f(hi));
        }
        *(short8*)&a_rbf[0][(l16*16 + ed)*8] = thi;
        *(short8*)&a_rbf[1][(l16*16 + ed)*8] = tlo;
    }
    {
        const float t = d - 0.4f * (float)l16;
        sh_es0[ed][l16] = expf(-3.125f * t * t);
    }

    const float rs80 = 0.11180339887498949f;   // 1/sqrt(80)
    const float rs32 = 0.17677669529663689f;   // 1/sqrt(32)
    {
        const float* fi = node_fea + (size_t)ni * 80;
        const float* fj = node_fea + (size_t)nj * 80;
        sh_sin[ed][2*l16+0]    = fi[2*l16+0] * rs80;
        sh_sin[ed][2*l16+1]    = fi[2*l16+1] * rs80;
        sh_sin[ed][32+2*l16+0] = fj[2*l16+0] * rs80;
        sh_sin[ed][32+2*l16+1] = fj[2*l16+1] * rs80;
        #pragma unroll
        for (int c = 0; c < 3; ++c) {
            sh_vl[ed][c][l16]      = fi[32 + 3*l16 + c] * rs32;
            sh_vl[ed][c][16 + l16] = fj[32 + 3*l16 + c] * rs32;
        }
    }
    for (int s = tid; s < 16*56; s += 256) (&sh_acc[0][0])[s] = 0.0f;
    __syncthreads();

    // pairing-corrected logical k for this lane's 8 B slots
    int km[8];
    #pragma unroll
    for (int j = 0; j < 8; ++j) km[j] = sh_kmap[quad*8 + j];

    // edge_s (scaled, into sin[64:80]) and sc
    {
        const int o = l16;
        float es = b_pre[o];
        float sc = 0.0f;
        const int p = 4*xsp[ni] + xsp[nj];
        #pragma unroll
        for (int i = 0; i < 16; ++i) {
            const float g = sh_es0[ed][i];
            es += g * w_pre[i*16 + o];
            sc += g * w_sc[(i*16 + p)*16 + o];
        }
        sh_sin[ed][64 + o] = es * rs80;
        sh_sc[ed][o] = sc * 0.0625f;            // / sqrt(16*16)
    }
    // q and cross
    #pragma unroll
    for (int rr = 0; rr < 2; ++rr) {
        const int i = l16 + 16*rr;
        const float a0 = sh_vl[ed][0][i];
        const float a1 = sh_vl[ed][1][i];
        const float a2 = sh_vl[ed][2][i];
        sh_q[ed][i] = (a0*Y0 + a1*Y1 + a2*Y2) * 0.57735026918962573f;
        sh_cr[ed][0][i] = (a1*Y2 - a2*Y1) * 0.70710678118654746f;
        sh_cr[ed][1][i] = (a2*Y0 - a0*Y2) * 0.70710678118654746f;
        sh_cr[ed][2][i] = (a0*Y1 - a1*Y0) * 0.70710678118654746f;
    }

    // h = silu(rbf @ w_rh + b_rh) via split MFMA; wave w -> h cols [w*16, w*16+16)
    {
        floatx4 hacc = {0.0f, 0.0f, 0.0f, 0.0f};
        #pragma unroll
        for (int kk = 0; kk < 4; ++kk) {
            const short8 ahi = *(const short8*)&a_rbf[0][((kk*4 + quad)*16 + l15)*8];
            const short8 alo = *(const short8*)&a_rbf[1][((kk*4 + quad)*16 + l15)*8];
            short8 bhi, blo;
            #pragma unroll
            for (int j = 0; j < 8; ++j) {
                const float wv = w_rh[(size_t)(kk*32 + km[j])*64 + w*16 + l15];
                const u16 h = f2bf(wv);
                bhi[j] = (short)h;
                blo[j] = (short)f2bf(wv - bfu2f(h));
            }
            hacc = __builtin_amdgcn_mfma_f32_16x16x32_bf16(ahi, bhi, hacc, 0, 0, 0);
            hacc = __builtin_amdgcn_mfma_f32_16x16x32_bf16(alo, bhi, hacc, 0, 0, 0);
            hacc = __builtin_amdgcn_mfma_f32_16x16x32_bf16(ahi, blo, hacc, 0, 0, 0);
        }
        const int hn = w*16 + l15;                // h column
        const float bb = b_rh[hn];
        const int k8 = hn >> 3, j2 = hn & 7;
        #pragma unroll
        for (int r = 0; r < 4; ++r) {
            const float x = hacc[r] + bb;
            const float s = x / (1.0f + expf(-x));
            const int m = quad*4 + r;             // edge row
            const u16 h = f2bf(s);
            a_h[0][(k8*16 + m)*8 + j2] = h;
            a_h[1][(k8*16 + m)*8 + j2] = f2bf(s - bfu2f(h));
        }
    }
    __syncthreads();

    // A-fragments for the main GEMM (constant across all chunks)
    const short8 a0h = *(const short8*)&a_h[0][((0*4 + quad)*16 + l15)*8];
    const short8 a1h = *(const short8*)&a_h[0][((1*4 + quad)*16 + l15)*8];
    const short8 a0l = *(const short8*)&a_h[1][((0*4 + quad)*16 + l15)*8];
    const short8 a1l = *(const short8*)&a_h[1][((1*4 + quad)*16 + l15)*8];

    // -------- main loop: w_all in 15 chunks of 256 cols; wave w -> cols [w*64,w*64+64) --------
    for (int ch = 0; ch < 15; ++ch) {
        const int coff = ch * 256;
        floatx4 acc[4];
        float bias[4];
        #pragma unroll
        for (int ct = 0; ct < 4; ++ct) {
            const int gct = ch*16 + w*4 + ct;     // global col-tile
            const float* wp = w_ro + gct*16 + l15;
            float f0[8], f1[8];
            #pragma unroll
            for (int j = 0; j < 8; ++j) {
                f0[j] = wp[(size_t)km[j]*3840];
                f1[j] = wp[(size_t)(km[j]+32)*3840];
            }
            short8 b0h, b0l, b1h, b1l;
            #pragma unroll
            for (int j = 0; j < 8; ++j) {
                const u16 h0 = f2bf(f0[j]);
                b0h[j] = (short)h0; b0l[j] = (short)f2bf(f0[j] - bfu2f(h0));
                const u16 h1 = f2bf(f1[j]);
                b1h[j] = (short)h1; b1l[j] = (short)f2bf(f1[j] - bfu2f(h1));
            }
            floatx4 a = {0.0f, 0.0f, 0.0f, 0.0f};
            a = __builtin_amdgcn_mfma_f32_16x16x32_bf16(a0h, b0h, a, 0, 0, 0);
            a = __builtin_amdgcn_mfma_f32_16x16x32_bf16(a1h, b1h, a, 0, 0, 0);
            a = __builtin_amdgcn_mfma_f32_16x16x32_bf16(a0l, b0h, a, 0, 0, 0);
            a = __builtin_amdgcn_mfma_f32_16x16x32_bf16(a1l, b1h, a, 0, 0, 0);
            a = __builtin_amdgcn_mfma_f32_16x16x32_bf16(a0h, b0l, a, 0, 0, 0);
            a = __builtin_amdgcn_mfma_f32_16x16x32_bf16(a1h, b1l, a, 0, 0, 0);
            acc[ct] = a;
            bias[ct] = b_ro[gct*16 + l15];
        }
        __syncthreads();   // previous chunk's consumers done with sh_wt
        #pragma unroll
        for (int ct = 0; ct < 4; ++ct) {
            const int col = w*64 + ct*16 + l15;
            #pragma unroll
            for (int r = 0; r < 4; ++r)
                sh_wt[quad*4 + r][col] = acc[ct][r] + bias[ct];
        }
        __syncthreads();

        if (ch <= 7) {  // w1: 80x24 (cols 0..1920), -> s_conv
            const int hi = (ch == 7) ? 1920 : (coff + 256);
            for (int idx = tid; idx < 384; idx += 256) {
                const int eo = idx / 24, o = idx % 24;
                const int i0 = (coff > o) ? (coff - o + 23) / 24 : 0;
                int i1 = (hi - o + 23) / 24; if (i1 > 80) i1 = 80;
                float a = 0.0f;
                for (int i = i0; i < i1; ++i)
                    a += sh_sin[eo][i] * sh_wt[eo][i*24 + o - coff];
                sh_acc[eo][o] += a;
            }
        }
        if (ch == 7) {  // w2 rows 0..15 (cols 1920..2047)
            for (int idx = tid; idx < 128; idx += 256) {
                const int eo = idx >> 3, o = idx & 7;
                float a = 0.0f;
                #pragma unroll
                for (int i = 0; i < 16; ++i)
                    a += sh_sin[eo][i] * sh_wt[eo][128 + i*8 + o];
                sh_acc[eo][24 + o] += a;
            }
        }
        if (ch == 8 || ch == 9) {  // w2 rows 16..47 / 48..79
            const int ib = (ch == 8) ? 16 : 48;
            for (int idx = tid; idx < 128; idx += 256) {
                const int eo = idx >> 3, o = idx & 7;
                float a = 0.0f;
                #pragma unroll
                for (int i2 = 0; i2 < 32; ++i2)
                    a += sh_sin[eo][ib + i2] * sh_wt[eo][i2*8 + o];
                sh_acc[eo][24 + o] += a;
            }
        }
        if (ch == 10) {  // w3: 32x8, left = v_in[:,c]
            for (int idx = tid; idx < 384; idx += 256) {
                const int eo = idx / 24, rem = idx % 24;
                const int o = rem / 3, cc = rem % 3;
                float a = 0.0f;
                #pragma unroll
                for (int i = 0; i < 32; ++i)
                    a += sh_vl[eo][cc][i] * sh_wt[eo][i*8 + o];
                sh_acc[eo][32 + o*3 + cc] += a;
            }
        }
        if (ch >= 11 && ch <= 13) {  // w4: 32x24, left = q, -> s_conv
            const int rel = coff - 2816;
            for (int idx = tid; idx < 384; idx += 256) {
                const int eo = idx / 24, o = idx % 24;
                const int i0 = (rel > o) ? (rel - o + 23) / 24 : 0;
                int i1 = (rel + 256 - o + 23) / 24; if (i1 > 32) i1 = 32;
                float a = 0.0f;
                for (int i = i0; i < i1; ++i)
                    a += sh_q[eo][i] * sh_wt[eo][i*24 + o - rel];
                sh_acc[eo][o] += a;
            }
        }
        if (ch == 14) {  // w5: 32x8, left = cross
            for (int idx = tid; idx < 384; idx += 256) {
                const int eo = idx / 24, rem = idx % 24;
                const int o = rem / 3, cc = rem % 3;
                float a = 0.0f;
                #pragma unroll
                for (int i = 0; i < 32; ++i)
                    a += sh_cr[eo][cc][i] * sh_wt[eo][i*8 + o];
                sh_acc[eo][32 + o*3 + cc] += a;
            }
        }
    }
    __syncthreads();

    // -------- epilogue: gate + post projections, f32 store into out --------
    {
        const int o = l16;
        float a = b_post_s[o] + sh_sc[ed][o];
        #pragma unroll
        for (int i = 0; i < 16; ++i) {
            const float sv = sh_acc[ed][i];
            a += (sv / (1.0f + expf(-sv))) * w_post_s[i*16 + o];
        }
        out[(size_t)e*40 + o] = a;
    }
    if (l16 < 8) {
        const int o = l16;
        const float Ya = sh_y1[ed][0], Yb = sh_y1[ed][1], Yc = sh_y1[ed][2];
        float r0 = 0.0f, r1 = 0.0f, r2 = 0.0f;
        #pragma unroll
        for (int i = 0; i < 8; ++i) {
            const float g  = 1.0f / (1.0f + expf(-sh_acc[ed][16 + i]));
            const float a2 = sh_acc[ed][24 + i];
            const float ww = w_post_v[i*8 + o];
            r0 += (a2*Ya + sh_acc[ed][32 + i*3 + 0]) * g * ww;
            r1 += (a2*Yb + sh_acc[ed][32 + i*3 + 1]) * g * ww;
            r2 += (a2*Yc + sh_acc[ed][32 + i*3 + 2]) * g * ww;
        }
        out[(size_t)e*40 + 16 + o*3 + 0] = r0;
        out[(size_t)e*40 + 16 + o*3 + 1] = r1;
        out[(size_t)e*40 + 16 + o*3 + 2] = r2;
    }
}

// ---------------- Kernel 2a: per-block segment-stat partials + atomicAdd ----------------
__global__ __launch_bounds__(256) void k_stats_partial(
    const float* __restrict__ sv, const int* __restrict__ edge_index,
    const int* __restrict__ batch, float* __restrict__ ws)
{
    __shared__ float sh_ed[256][40];
    __shared__ int   sh_eb[256];
    const int tid = threadIdx.x;
    const int e = blockIdx.x * 256 + tid;
    sh_eb[tid] = batch[edge_index[e]];
    const float* p = sv + (size_t)e * 40;
    #pragma unroll
    for (int j = 0; j < 40; ++j) sh_ed[tid][j] = p[j];
    __syncthreads();

    for (int slot = tid; slot < 768; slot += 256) {
        const int g = slot / 48, s = slot % 48;
        float acc = 0.0f;
        if (s < 16) {
            for (int k = 0; k < 256; ++k) {
                const float m = (sh_eb[k] == g) ? 1.0f : 0.0f;
                acc += m * sh_ed[k][s];
            }
        } else if (s < 32) {
            for (int k = 0; k < 256; ++k) {
                const float m = (sh_eb[k] == g) ? 1.0f : 0.0f;
                const float v = sh_ed[k][s - 16];
                acc += m * v * v;
            }
        } else if (s < 40) {
            const int o3 = 16 + (s - 32) * 3;
            for (int k = 0; k < 256; ++k) {
                const float m = (sh_eb[k] == g) ? 1.0f : 0.0f;
                const float v0 = sh_ed[k][o3], v1 = sh_ed[k][o3+1], v2 = sh_ed[k][o3+2];
                acc += m * (v0*v0 + v1*v1 + v2*v2);
            }
        } else if (s == 40) {
            for (int k = 0; k < 256; ++k) acc += (sh_eb[k] == g) ? 1.0f : 0.0f;
        }
        atomicAdd(&ws[slot], acc);
    }
}

// ---------------- Kernel 2b: finalize per-graph mu / inv_rms ----------------
__global__ __launch_bounds__(64) void k_stats_final(float* __restrict__ ws)
{
    const int tid = threadIdx.x;
    if (tid < 16) {
        const int g = tid;
        float cnt = ws[g*48 + 40]; if (cnt < 1.0f) cnt = 1.0f;
        const float ic = 1.0f / cnt;
        float vs = 0.0f;
        for (int chn = 0; chn < 16; ++chn) {
            const float mu = ws[g*48 + chn] * ic;
            ws[768 + g*16 + chn] = mu;
            vs += ws[g*48 + 16 + chn] * ic - mu * mu;
        }
        if (vs < 0.0f) vs = 0.0f;
        ws[1024 + g] = 1.0f / sqrtf(vs * (1.0f/16.0f) + 1e-5f);
        float vv = 0.0f;
        for (int o = 0; o < 8; ++o) vv += ws[g*48 + 32 + o];
        vv = vv * ic * (1.0f/3.0f) * (1.0f/8.0f);
        ws[1040 + g] = 1.0f / sqrtf(vv + 1e-5f);
    }
}

// ---------------- Kernel 4: LN + skip + edge projections, in place on out ----------------
__global__ __launch_bounds__(256) void k_edge_final(
    float* buf, const float* __restrict__ ws,
    const float* __restrict__ edge_attr, const int* __restrict__ edge_index,
    const int* __restrict__ batch,
    const float* __restrict__ ln_w_s, const float* __restrict__ ln_b_s,
    const float* __restrict__ ln_w_v, const float* __restrict__ w_skip,
    const float* __restrict__ w_edge_s, const float* __restrict__ b_edge_s,
    const float* __restrict__ w_edge_v)
{
    __shared__ float sh_mu[16][16];
    __shared__ float sh_is[16], sh_iv[16];
    __shared__ float sh_lws[16], sh_lbs[16], sh_lwv[8];
    __shared__ float sh_skip[16][16], sh_wes[16][16], sh_bes[16], sh_wev[8][8];
    const int tid = threadIdx.x;
    sh_mu[tid >> 4][tid & 15]   = ws[768 + tid];
    sh_skip[tid >> 4][tid & 15] = w_skip[tid];
    sh_wes[tid >> 4][tid & 15]  = w_edge_s[tid];
    if (tid < 16) {
        sh_is[tid]  = ws[1024 + tid];
        sh_iv[tid]  = ws[1040 + tid];
        sh_lws[tid] = ln_w_s[tid];
        sh_lbs[tid] = ln_b_s[tid];
        sh_bes[tid] = b_edge_s[tid];
    }
    if (tid < 8)  sh_lwv[tid] = ln_w_v[tid];
    if (tid < 64) sh_wev[tid >> 3][tid & 7] = w_edge_v[tid];
    __syncthreads();

    const int e = blockIdx.x * 256 + tid;
    const int g = batch[edge_index[e]];
    const float d = edge_attr[4*e];
    float es0[16];
    #pragma unroll
    for (int b = 0; b < 16; ++b) {
        const float t = d - 0.4f * (float)b;
        es0[b] = expf(-3.125f * t * t);
    }
    float p[40];
    float* pb = buf + (size_t)e * 40;
    #pragma unroll
    for (int j = 0; j < 40; ++j) p[j] = pb[j];

    const float is = sh_is[g];
    float sn[16];
    #pragma unroll
    for (int chn = 0; chn < 16; ++chn)
        sn[chn] = (p[chn] - sh_mu[g][chn]) * is * sh_lws[chn] + sh_lbs[chn];
    #pragma unroll
    for (int b = 0; b < 16; ++b) {
        const float g0 = es0[b];
        #pragma unroll
        for (int chn = 0; chn < 16; ++chn) sn[chn] += g0 * sh_skip[b][chn];
    }
    #pragma unroll
    for (int o = 0; o < 16; ++o) {
        float a = sh_bes[o];
        #pragma unroll
        for (int chn = 0; chn < 16; ++chn) a += sn[chn] * sh_wes[chn][o];
        pb[o] = a;
    }
    const float iv = sh_iv[g];
    float vn[8][3];
    #pragma unroll
    for (int i = 0; i < 8; ++i) {
        const float f = iv * sh_lwv[i];
        vn[i][0] = p[16 + i*3 + 0] * f;
        vn[i][1] = p[16 + i*3 + 1] * f;
        vn[i][2] = p[16 + i*3 + 2] * f;
    }
    #pragma unroll
    for (int o = 0; o < 8; ++o) {
        float r0 = 0.0f, r1 = 0.0f, r2 = 0.0f;
        #pragma unroll
        for (int i = 0; i < 8; ++i) {
            const float w = sh_wev[i][o];
            r0 += vn[i][0] * w; r1 += vn[i][1] * w; r2 += vn[i][2] * w;
        }
        pb[16 + o*3 + 0] = r0;
        pb[16 + o*3 + 1] = r1;
        pb[16 + o*3 + 2] = r2;
    }
}

extern "C" void kernel_launch(void* const* d_in, const int* in_sizes, int n_in,
                              void* d_out, int out_size, void* d_ws, size_t ws_size,
                              hipStream_t stream)
{
    const float* node_fea  = (const float*)d_in[0];
    const float* edge_attr = (const float*)d_in[1];
    const int* edge_index  = (const int*)d_in[2];
    const int* xsp         = (const int*)d_in[3];
    const int* batch       = (const int*)d_in[4];
    const float* w_rh      = (const float*)d_in[5];
    const float* b_rh      = (const float*)d_in[6];
    const float* w_ro      = (const float*)d_in[7];
    const float* b_ro      = (const float*)d_in[8];
    const float* w_pre     = (const float*)d_in[9];
    const float* b_pre     = (const float*)d_in[10];
    const float* w_sc      = (const float*)d_in[11];
    const float* w_post_s  = (const float*)d_in[12];
    const float* b_post_s  = (const float*)d_in[13];
    const float* w_post_v  = (const float*)d_in[14];
    const float* ln_w_s    = (const float*)d_in[15];
    const float* ln_b_s    = (const float*)d_in[16];
    const float* ln_w_v    = (const float*)d_in[17];
    const float* w_skip    = (const float*)d_in[18];
    const float* w_edge_s  = (const float*)d_in[19];
    const float* b_edge_s  = (const float*)d_in[20];
    const float* w_edge_v  = (const float*)d_in[21];

    float* ws   = (float*)d_ws;          // 1056 floats + 32 ints (~4.3 KB)
    int*   binv = (int*)(ws + 1056);
    float* out  = (float*)d_out;

    k_zero<<<2, 1024, 0, stream>>>(ws);
    k_probe<<<1, 64, 0, stream>>>(binv);
    k_edge_heavy<<<4096, 256, 0, stream>>>(node_fea, edge_attr, edge_index, xsp,
        w_rh, b_rh, w_ro, b_ro, w_pre, b_pre, w_sc, w_post_s, b_post_s, w_post_v,
        binv, out);
    k_stats_partial<<<256, 256, 0, stream>>>(out, edge_index, batch, ws);
    k_stats_final<<<1, 64, 0, stream>>>(ws);
    k_edge_final<<<256, 256, 0, stream>>>(out, ws, edge_attr, edge_index,
        batch, ln_w_s, ln_b_s, ln_w_v, w_skip, w_edge_s, b_edge_s, w_edge_v);
}

// Round 9
// 483.821 us; speedup vs baseline: 1.7823x; 1.2494x over previous
//
#include <hip/hip_runtime.h>

typedef unsigned short u16;
typedef unsigned int u32;
typedef __attribute__((ext_vector_type(8))) short short8;
typedef __attribute__((ext_vector_type(4))) float floatx4;

#define E_TOTAL 65536

__device__ __forceinline__ u16 f2bf(float f) {
    union { float f; u32 i; } c; c.f = f;
    const u32 u = c.i;
    const u32 r = (u + 0x7fffu + ((u >> 16) & 1u)) >> 16;   // RNE, finite inputs
    return (u16)r;
}
__device__ __forceinline__ float bfu2f(u16 u) {
    union { u32 i; float f; } c; c.i = ((u32)u) << 16; return c.f;
}
// RTZ hi/lo split of two floats, packed into bf16x2 words (e0 low, e1 high).
__device__ __forceinline__ void split2(float x0, float x1, u32& hp, u32& lp) {
    union { float f; u32 u; } a0, a1, h0, h1, l0, l1;
    a0.f = x0; a1.f = x1;
    h0.u = a0.u & 0xFFFF0000u; h1.u = a1.u & 0xFFFF0000u;
    hp = __builtin_amdgcn_perm(a1.u, a0.u, 0x07060302u);    // [e0.hi16 | e1.hi16]
    l0.f = x0 - h0.f; l1.f = x1 - h1.f;                     // exact residuals
    lp = __builtin_amdgcn_perm(l1.u, l0.u, 0x07060302u);    // RTZ of residuals
}
union Frag8 { u32 u[4]; short8 s; };

// ws layout (floats): [0:768] per-graph stat sums, [768:1024] mu, [1024:1040] irs,
// [1040:1056] irv; ints [1056:1088] = binv (B-slot -> logical k pairing map)

__global__ void k_zero(float* __restrict__ ws) {
    const int i = threadIdx.x + blockIdx.x * blockDim.x;
    if (i < 1056) ws[i] = 0.0f;
}

// ---------------- Probe: measure A-slot <-> B-slot k-pairing of mfma_16x16x32_bf16 ----
__global__ __launch_bounds__(64) void k_probe(int* __restrict__ binv) {
    const int lane = threadIdx.x;
    const int q = lane >> 4;
    if (lane < 32) binv[lane] = lane;    // default identity (safety)
    short8 bfr;
    #pragma unroll
    for (int j = 0; j < 8; ++j) bfr[j] = (short)f2bf((float)(q*8 + j + 1));
    #pragma unroll
    for (int s = 0; s < 32; ++s) {
        const int qa = s >> 3, ja = s & 7;
        short8 afr = {0,0,0,0,0,0,0,0};
        if (q == qa) afr[ja] = (short)f2bf(1.0f);
        floatx4 dc = {0.0f, 0.0f, 0.0f, 0.0f};
        dc = __builtin_amdgcn_mfma_f32_16x16x32_bf16(afr, bfr, dc, 0, 0, 0);
        if (lane == 0) {
            const int sB = (int)(dc[0] + 0.5f) - 1;   // B-slot paired with A-slot s
            if (sB >= 0 && sB < 32) binv[sB] = s;     // logical k of that B-slot
        }
    }
}

// ---------------- Kernel 1: heavy per-edge conv (split-precision MFMA) ----------------
__global__ __launch_bounds__(256) void k_edge_heavy(
    const float* __restrict__ node_fea, const float* __restrict__ edge_attr,
    const int* __restrict__ edge_index, const int* __restrict__ xsp,
    const float* __restrict__ w_rh, const float* __restrict__ b_rh,
    const float* __restrict__ w_ro, const float* __restrict__ b_ro,
    const float* __restrict__ w_pre, const float* __restrict__ b_pre,
    const float* __restrict__ w_sc, const float* __restrict__ w_post_s,
    const float* __restrict__ b_post_s, const float* __restrict__ w_post_v,
    const int* __restrict__ binv,
    float* __restrict__ out)
{
    __shared__ __align__(16) u16 a_rbf[2][16 * 128]; // [hi|lo] A-frag: (m,k) at ((k>>3)*16+m)*8+(k&7)
    __shared__ __align__(16) u16 a_h[2][16 * 64];    // [hi|lo] same convention, K=64
    __shared__ __align__(16) float sh_wt[16][258];   // w_all chunk tile (pad 258)
    __shared__ float sh_sin[16][80];    // s_in * (1/sqrt80)
    __shared__ float sh_vl[16][3][32];  // v_in[c][i] * (1/sqrt32)
    __shared__ float sh_q[16][32];      // (v_in . Y1) * (1/sqrt96)
    __shared__ float sh_cr[16][3][32];  // cross(v_in,Y1)[c][i] * (1/sqrt64)
    __shared__ float sh_acc[16][56];    // [0:24]=s_conv, [24:32]=a2(vA), [32:56]=v(o,c)
    __shared__ float sh_es0[16][16];
    __shared__ float sh_y1[16][4];
    __shared__ int   sh_kmap[32];

    const int tid = threadIdx.x;
    const int ed = tid >> 4, l16 = tid & 15;
    const int lane = tid & 63, w = tid >> 6;
    const int quad = lane >> 4, l15 = lane & 15;
    const int e = blockIdx.x * 16 + ed;

    if (tid < 32) sh_kmap[tid] = binv[tid];

    const int ni = edge_index[e];
    const int nj = edge_index[E_TOTAL + e];
    const float4 ea = *(const float4*)(edge_attr + 4*e);
    const float d  = ea.x;
    const float vx = ea.y, vy = ea.z, vz = ea.w;
    const float invn = 1.0f / (sqrtf(vx*vx + vy*vy + vz*vz) + 1e-12f);
    const float Y0 = 1.7320508075688772f * vx * invn;
    const float Y1 = 1.7320508075688772f * vy * invn;
    const float Y2 = 1.7320508075688772f * vz * invn;
    if (l16 == 0) { sh_y1[ed][0] = Y0; sh_y1[ed][1] = Y1; sh_y1[ed][2] = Y2; }

    // rbf -> hi/lo bf16 A-fragments
    const float C128 = -0.5f * (127.0f/6.0f) * (127.0f/6.0f);
    const float S128 = 6.0f/127.0f;
    {
        short8 thi, tlo;
        #pragma unroll
        for (int r = 0; r < 8; ++r) {
            const int b = l16*8 + r;
            const float t = d - S128 * (float)b;
            const float x = expf(C128 * t * t);
            const u16 hi = f2bf(x);
            thi[r] = (short)hi;
            tlo[r] = (short)f2bf(x - bfu2f(hi));
        }
        *(short8*)&a_rbf[0][(l16*16 + ed)*8] = thi;
        *(short8*)&a_rbf[1][(l16*16 + ed)*8] = tlo;
    }
    {
        const float t = d - 0.4f * (float)l16;
        sh_es0[ed][l16] = expf(-3.125f * t * t);
    }

    const float rs80 = 0.11180339887498949f;   // 1/sqrt(80)
    const float rs32 = 0.17677669529663689f;   // 1/sqrt(32)
    {
        const float* fi = node_fea + (size_t)ni * 80;
        const float* fj = node_fea + (size_t)nj * 80;
        sh_sin[ed][2*l16+0]    = fi[2*l16+0] * rs80;
        sh_sin[ed][2*l16+1]    = fi[2*l16+1] * rs80;
        sh_sin[ed][32+2*l16+0] = fj[2*l16+0] * rs80;
        sh_sin[ed][32+2*l16+1] = fj[2*l16+1] * rs80;
        #pragma unroll
        for (int c = 0; c < 3; ++c) {
            sh_vl[ed][c][l16]      = fi[32 + 3*l16 + c] * rs32;
            sh_vl[ed][c][16 + l16] = fj[32 + 3*l16 + c] * rs32;
        }
    }
    for (int s = tid; s < 16*56; s += 256) (&sh_acc[0][0])[s] = 0.0f;
    __syncthreads();

    // pairing-corrected logical k for this lane's 8 B slots + load offsets
    int km[8];
    u32 voff0[8], voff1[8];
    #pragma unroll
    for (int j = 0; j < 8; ++j) {
        km[j] = sh_kmap[quad*8 + j];
        voff0[j] = (u32)(km[j] * 3840 + l15);
        voff1[j] = voff0[j] + 32u * 3840u;
    }

    // edge_s (scaled, into sin[64:80]) and sc (register: same thread consumes it)
    float my_sc;
    {
        const int o = l16;
        float es = b_pre[o];
        float sc = 0.0f;
        const int p = 4*xsp[ni] + xsp[nj];
        #pragma unroll
        for (int i = 0; i < 16; ++i) {
            const float g = sh_es0[ed][i];
            es += g * w_pre[i*16 + o];
            sc += g * w_sc[(i*16 + p)*16 + o];
        }
        sh_sin[ed][64 + o] = es * rs80;
        my_sc = sc * 0.0625f;                   // / sqrt(16*16)
    }
    // q and cross
    #pragma unroll
    for (int rr = 0; rr < 2; ++rr) {
        const int i = l16 + 16*rr;
        const float a0 = sh_vl[ed][0][i];
        const float a1 = sh_vl[ed][1][i];
        const float a2 = sh_vl[ed][2][i];
        sh_q[ed][i] = (a0*Y0 + a1*Y1 + a2*Y2) * 0.57735026918962573f;
        sh_cr[ed][0][i] = (a1*Y2 - a2*Y1) * 0.70710678118654746f;
        sh_cr[ed][1][i] = (a2*Y0 - a0*Y2) * 0.70710678118654746f;
        sh_cr[ed][2][i] = (a0*Y1 - a1*Y0) * 0.70710678118654746f;
    }

    // h = silu(rbf @ w_rh + b_rh) via split MFMA; wave w -> h cols [w*16, w*16+16)
    {
        floatx4 hacc = {0.0f, 0.0f, 0.0f, 0.0f};
        #pragma unroll
        for (int kk = 0; kk < 4; ++kk) {
            const short8 ahi = *(const short8*)&a_rbf[0][((kk*4 + quad)*16 + l15)*8];
            const short8 alo = *(const short8*)&a_rbf[1][((kk*4 + quad)*16 + l15)*8];
            Frag8 bh, bl;
            #pragma unroll
            for (int jj = 0; jj < 4; ++jj) {
                const float x0 = w_rh[(size_t)(kk*32 + km[2*jj+0])*64 + w*16 + l15];
                const float x1 = w_rh[(size_t)(kk*32 + km[2*jj+1])*64 + w*16 + l15];
                split2(x0, x1, bh.u[jj], bl.u[jj]);
            }
            hacc = __builtin_amdgcn_mfma_f32_16x16x32_bf16(ahi, bh.s, hacc, 0, 0, 0);
            hacc = __builtin_amdgcn_mfma_f32_16x16x32_bf16(alo, bh.s, hacc, 0, 0, 0);
            hacc = __builtin_amdgcn_mfma_f32_16x16x32_bf16(ahi, bl.s, hacc, 0, 0, 0);
        }
        const int hn = w*16 + l15;                // h column
        const float bb = b_rh[hn];
        const int k8 = hn >> 3, j2 = hn & 7;
        #pragma unroll
        for (int r = 0; r < 4; ++r) {
            const float x = hacc[r] + bb;
            const float s = x / (1.0f + expf(-x));
            const int m = quad*4 + r;             // edge row
            const u16 h = f2bf(s);
            a_h[0][(k8*16 + m)*8 + j2] = h;
            a_h[1][(k8*16 + m)*8 + j2] = f2bf(s - bfu2f(h));
        }
    }
    __syncthreads();

    // A-fragments for the main GEMM (constant across all chunks)
    const short8 a0h = *(const short8*)&a_h[0][((0*4 + quad)*16 + l15)*8];
    const short8 a1h = *(const short8*)&a_h[0][((1*4 + quad)*16 + l15)*8];
    const short8 a0l = *(const short8*)&a_h[1][((0*4 + quad)*16 + l15)*8];
    const short8 a1l = *(const short8*)&a_h[1][((1*4 + quad)*16 + l15)*8];

    // -------- main loop: w_all in 15 chunks of 256 cols; wave w -> cols [w*64,w*64+64) --------
    for (int ch = 0; ch < 15; ++ch) {
        const int coff = ch * 256;
        floatx4 acc[4];
        float bias[4];
        #pragma unroll
        for (int ct = 0; ct < 4; ++ct) {
            const int sgct = __builtin_amdgcn_readfirstlane(ch*16 + w*4 + ct); // wave-uniform col-tile
            const float* bp = w_ro + sgct*16;     // scalar base -> saddr-form loads
            float f0[8], f1[8];
            #pragma unroll
            for (int j = 0; j < 8; ++j) {
                f0[j] = bp[voff0[j]];
                f1[j] = bp[voff1[j]];
            }
            Frag8 b0h, b0l, b1h, b1l;
            #pragma unroll
            for (int jj = 0; jj < 4; ++jj) {
                split2(f0[2*jj], f0[2*jj+1], b0h.u[jj], b0l.u[jj]);
                split2(f1[2*jj], f1[2*jj+1], b1h.u[jj], b1l.u[jj]);
            }
            floatx4 a = {0.0f, 0.0f, 0.0f, 0.0f};
            a = __builtin_amdgcn_mfma_f32_16x16x32_bf16(a0h, b0h.s, a, 0, 0, 0);
            a = __builtin_amdgcn_mfma_f32_16x16x32_bf16(a1h, b1h.s, a, 0, 0, 0);
            a = __builtin_amdgcn_mfma_f32_16x16x32_bf16(a0l, b0h.s, a, 0, 0, 0);
            a = __builtin_amdgcn_mfma_f32_16x16x32_bf16(a1l, b1h.s, a, 0, 0, 0);
            a = __builtin_amdgcn_mfma_f32_16x16x32_bf16(a0h, b0l.s, a, 0, 0, 0);
            a = __builtin_amdgcn_mfma_f32_16x16x32_bf16(a1h, b1l.s, a, 0, 0, 0);
            acc[ct] = a;
            bias[ct] = b_ro[sgct*16 + l15];
        }
        __syncthreads();   // previous chunk's consumers done with sh_wt
        #pragma unroll
        for (int ct = 0; ct < 4; ++ct) {
            const int col = w*64 + ct*16 + l15;
            #pragma unroll
            for (int r = 0; r < 4; ++r)
                sh_wt[quad*4 + r][col] = acc[ct][r] + bias[ct];
        }
        __syncthreads();

        if (ch <= 7) {  // w1: 80x24 (cols 0..1920), -> s_conv
            const int hi = (ch == 7) ? 1920 : (coff + 256);
            for (int idx = tid; idx < 384; idx += 256) {
                const int eo = idx / 24, o = idx % 24;
                const int i0 = (coff > o) ? (coff - o + 23) / 24 : 0;
                int i1 = (hi - o + 23) / 24; if (i1 > 80) i1 = 80;
                float a = 0.0f;
                for (int i = i0; i < i1; ++i)
                    a += sh_sin[eo][i] * sh_wt[eo][i*24 + o - coff];
                sh_acc[eo][o] += a;
            }
        }
        if (ch == 7) {  // w2 rows 0..15 (cols 1920..2047)
            for (int idx = tid; idx < 128; idx += 256) {
                const int eo = idx >> 3, o = idx & 7;
                float a = 0.0f;
                #pragma unroll
                for (int i = 0; i < 16; ++i)
                    a += sh_sin[eo][i] * sh_wt[eo][128 + i*8 + o];
                sh_acc[eo][24 + o] += a;
            }
        }
        if (ch == 8 || ch == 9) {  // w2 rows 16..47 / 48..79
            const int ib = (ch == 8) ? 16 : 48;
            for (int idx = tid; idx < 128; idx += 256) {
                const int eo = idx >> 3, o = idx & 7;
                float a = 0.0f;
                #pragma unroll
                for (int i2 = 0; i2 < 32; ++i2)
                    a += sh_sin[eo][ib + i2] * sh_wt[eo][i2*8 + o];
                sh_acc[eo][24 + o] += a;
            }
        }
        if (ch == 10) {  // w3: 32x8, left = v_in[:,c]
            for (int idx = tid; idx < 384; idx += 256) {
                const int eo = idx / 24, rem = idx % 24;
                const int o = rem / 3, cc = rem % 3;
                float a = 0.0f;
                #pragma unroll
                for (int i = 0; i < 32; ++i)
                    a += sh_vl[eo][cc][i] * sh_wt[eo][i*8 + o];
                sh_acc[eo][32 + o*3 + cc] += a;
            }
        }
        if (ch >= 11 && ch <= 13) {  // w4: 32x24, left = q, -> s_conv
            const int rel = coff - 2816;
            for (int idx = tid; idx < 384; idx += 256) {
                const int eo = idx / 24, o = idx % 24;
                const int i0 = (rel > o) ? (rel - o + 23) / 24 : 0;
                int i1 = (rel + 256 - o + 23) / 24; if (i1 > 32) i1 = 32;
                float a = 0.0f;
                for (int i = i0; i < i1; ++i)
                    a += sh_q[eo][i] * sh_wt[eo][i*24 + o - rel];
                sh_acc[eo][o] += a;
            }
        }
        if (ch == 14) {  // w5: 32x8, left = cross
            for (int idx = tid; idx < 384; idx += 256) {
                const int eo = idx / 24, rem = idx % 24;
                const int o = rem / 3, cc = rem % 3;
                float a = 0.0f;
                #pragma unroll
                for (int i = 0; i < 32; ++i)
                    a += sh_cr[eo][cc][i] * sh_wt[eo][i*8 + o];
                sh_acc[eo][32 + o*3 + cc] += a;
            }
        }
    }
    __syncthreads();

    // -------- epilogue: gate + post projections, f32 store into out --------
    {
        const int o = l16;
        float a = b_post_s[o] + my_sc;
        #pragma unroll
        for (int i = 0; i < 16; ++i) {
            const float sv = sh_acc[ed][i];
            a += (sv / (1.0f + expf(-sv))) * w_post_s[i*16 + o];
        }
        out[(size_t)e*40 + o] = a;
    }
    if (l16 < 8) {
        const int o = l16;
        const float Ya = sh_y1[ed][0], Yb = sh_y1[ed][1], Yc = sh_y1[ed][2];
        float r0 = 0.0f, r1 = 0.0f, r2 = 0.0f;
        #pragma unroll
        for (int i = 0; i < 8; ++i) {
            const float g  = 1.0f / (1.0f + expf(-sh_acc[ed][16 + i]));
            const float a2 = sh_acc[ed][24 + i];
            const float ww = w_post_v[i*8 + o];
            r0 += (a2*Ya + sh_acc[ed][32 + i*3 + 0]) * g * ww;
            r1 += (a2*Yb + sh_acc[ed][32 + i*3 + 1]) * g * ww;
            r2 += (a2*Yc + sh_acc[ed][32 + i*3 + 2]) * g * ww;
        }
        out[(size_t)e*40 + 16 + o*3 + 0] = r0;
        out[(size_t)e*40 + 16 + o*3 + 1] = r1;
        out[(size_t)e*40 + 16 + o*3 + 2] = r2;
    }
}

// ---------------- Kernel 2a: per-block segment-stat partials + atomicAdd ----------------
__global__ __launch_bounds__(256) void k_stats_partial(
    const float* __restrict__ sv, const int* __restrict__ edge_index,
    const int* __restrict__ batch, float* __restrict__ ws)
{
    __shared__ float sh_ed[256][40];
    __shared__ int   sh_eb[256];
    const int tid = threadIdx.x;
    const int e = blockIdx.x * 256 + tid;
    sh_eb[tid] = batch[edge_index[e]];
    const float* p = sv + (size_t)e * 40;
    #pragma unroll
    for (int j = 0; j < 40; ++j) sh_ed[tid][j] = p[j];
    __syncthreads();

    for (int slot = tid; slot < 768; slot += 256) {
        const int g = slot / 48, s = slot % 48;
        float acc = 0.0f;
        if (s < 16) {
            for (int k = 0; k < 256; ++k) {
                const float m = (sh_eb[k] == g) ? 1.0f : 0.0f;
                acc += m * sh_ed[k][s];
            }
        } else if (s < 32) {
            for (int k = 0; k < 256; ++k) {
                const float m = (sh_eb[k] == g) ? 1.0f : 0.0f;
                const float v = sh_ed[k][s - 16];
                acc += m * v * v;
            }
        } else if (s < 40) {
            const int o3 = 16 + (s - 32) * 3;
            for (int k = 0; k < 256; ++k) {
                const float m = (sh_eb[k] == g) ? 1.0f : 0.0f;
                const float v0 = sh_ed[k][o3], v1 = sh_ed[k][o3+1], v2 = sh_ed[k][o3+2];
                acc += m * (v0*v0 + v1*v1 + v2*v2);
            }
        } else if (s == 40) {
            for (int k = 0; k < 256; ++k) acc += (sh_eb[k] == g) ? 1.0f : 0.0f;
        }
        atomicAdd(&ws[slot], acc);
    }
}

// ---------------- Kernel 2b: finalize per-graph mu / inv_rms ----------------
__global__ __launch_bounds__(64) void k_stats_final(float* __restrict__ ws)
{
    const int tid = threadIdx.x;
    if (tid < 16) {
        const int g = tid;
        float cnt = ws[g*48 + 40]; if (cnt < 1.0f) cnt = 1.0f;
        const float ic = 1.0f / cnt;
        float vs = 0.0f;
        for (int chn = 0; chn < 16; ++chn) {
            const float mu = ws[g*48 + chn] * ic;
            ws[768 + g*16 + chn] = mu;
            vs += ws[g*48 + 16 + chn] * ic - mu * mu;
        }
        if (vs < 0.0f) vs = 0.0f;
        ws[1024 + g] = 1.0f / sqrtf(vs * (1.0f/16.0f) + 1e-5f);
        float vv = 0.0f;
        for (int o = 0; o < 8; ++o) vv += ws[g*48 + 32 + o];
        vv = vv * ic * (1.0f/3.0f) * (1.0f/8.0f);
        ws[1040 + g] = 1.0f / sqrtf(vv + 1e-5f);
    }
}

// ---------------- Kernel 4: LN + skip + edge projections, in place on out ----------------
__global__ __launch_bounds__(256) void k_edge_final(
    float* buf, const float* __restrict__ ws,
    const float* __restrict__ edge_attr, const int* __restrict__ edge_index,
    const int* __restrict__ batch,
    const float* __restrict__ ln_w_s, const float* __restrict__ ln_b_s,
    const float* __restrict__ ln_w_v, const float* __restrict__ w_skip,
    const float* __restrict__ w_edge_s, const float* __restrict__ b_edge_s,
    const float* __restrict__ w_edge_v)
{
    __shared__ float sh_mu[16][16];
    __shared__ float sh_is[16], sh_iv[16];
    __shared__ float sh_lws[16], sh_lbs[16], sh_lwv[8];
    __shared__ float sh_skip[16][16], sh_wes[16][16], sh_bes[16], sh_wev[8][8];
    const int tid = threadIdx.x;
    sh_mu[tid >> 4][tid & 15]   = ws[768 + tid];
    sh_skip[tid >> 4][tid & 15] = w_skip[tid];
    sh_wes[tid >> 4][tid & 15]  = w_edge_s[tid];
    if (tid < 16) {
        sh_is[tid]  = ws[1024 + tid];
        sh_iv[tid]  = ws[1040 + tid];
        sh_lws[tid] = ln_w_s[tid];
        sh_lbs[tid] = ln_b_s[tid];
        sh_bes[tid] = b_edge_s[tid];
    }
    if (tid < 8)  sh_lwv[tid] = ln_w_v[tid];
    if (tid < 64) sh_wev[tid >> 3][tid & 7] = w_edge_v[tid];
    __syncthreads();

    const int e = blockIdx.x * 256 + tid;
    const int g = batch[edge_index[e]];
    const float d = edge_attr[4*e];
    float es0[16];
    #pragma unroll
    for (int b = 0; b < 16; ++b) {
        const float t = d - 0.4f * (float)b;
        es0[b] = expf(-3.125f * t * t);
    }
    float p[40];
    float* pb = buf + (size_t)e * 40;
    #pragma unroll
    for (int j = 0; j < 40; ++j) p[j] = pb[j];

    const float is = sh_is[g];
    float sn[16];
    #pragma unroll
    for (int chn = 0; chn < 16; ++chn)
        sn[chn] = (p[chn] - sh_mu[g][chn]) * is * sh_lws[chn] + sh_lbs[chn];
    #pragma unroll
    for (int b = 0; b < 16; ++b) {
        const float g0 = es0[b];
        #pragma unroll
        for (int chn = 0; chn < 16; ++chn) sn[chn] += g0 * sh_skip[b][chn];
    }
    #pragma unroll
    for (int o = 0; o < 16; ++o) {
        float a = sh_bes[o];
        #pragma unroll
        for (int chn = 0; chn < 16; ++chn) a += sn[chn] * sh_wes[chn][o];
        pb[o] = a;
    }
    const float iv = sh_iv[g];
    float vn[8][3];
    #pragma unroll
    for (int i = 0; i < 8; ++i) {
        const float f = iv * sh_lwv[i];
        vn[i][0] = p[16 + i*3 + 0] * f;
        vn[i][1] = p[16 + i*3 + 1] * f;
        vn[i][2] = p[16 + i*3 + 2] * f;
    }
    #pragma unroll
    for (int o = 0; o < 8; ++o) {
        float r0 = 0.0f, r1 = 0.0f, r2 = 0.0f;
        #pragma unroll
        for (int i = 0; i < 8; ++i) {
            const float w = sh_wev[i][o];
            r0 += vn[i][0] * w; r1 += vn[i][1] * w; r2 += vn[i][2] * w;
        }
        pb[16 + o*3 + 0] = r0;
        pb[16 + o*3 + 1] = r1;
        pb[16 + o*3 + 2] = r2;
    }
}

extern "C" void kernel_launch(void* const* d_in, const int* in_sizes, int n_in,
                              void* d_out, int out_size, void* d_ws, size_t ws_size,
                              hipStream_t stream)
{
    const float* node_fea  = (const float*)d_in[0];
    const float* edge_attr = (const float*)d_in[1];
    const int* edge_index  = (const int*)d_in[2];
    const int* xsp         = (const int*)d_in[3];
    const int* batch       = (const int*)d_in[4];
    const float* w_rh      = (const float*)d_in[5];
    const float* b_rh      = (const float*)d_in[6];
    const float* w_ro      = (const float*)d_in[7];
    const float* b_ro      = (const float*)d_in[8];
    const float* w_pre     = (const float*)d_in[9];
    const float* b_pre     = (const float*)d_in[10];
    const float* w_sc      = (const float*)d_in[11];
    const float* w_post_s  = (const float*)d_in[12];
    const float* b_post_s  = (const float*)d_in[13];
    const float* w_post_v  = (const float*)d_in[14];
    const float* ln_w_s    = (const float*)d_in[15];
    const float* ln_b_s    = (const float*)d_in[16];
    const float* ln_w_v    = (const float*)d_in[17];
    const float* w_skip    = (const float*)d_in[18];
    const float* w_edge_s  = (const float*)d_in[19];
    const float* b_edge_s  = (const float*)d_in[20];
    const float* w_edge_v  = (const float*)d_in[21];

    float* ws   = (float*)d_ws;          // 1056 floats + 32 ints (~4.3 KB)
    int*   binv = (int*)(ws + 1056);
    float* out  = (float*)d_out;

    k_zero<<<2, 1024, 0, stream>>>(ws);
    k_probe<<<1, 64, 0, stream>>>(binv);
    k_edge_heavy<<<4096, 256, 0, stream>>>(node_fea, edge_attr, edge_index, xsp,
        w_rh, b_rh, w_ro, b_ro, w_pre, b_pre, w_sc, w_post_s, b_post_s, w_post_v,
        binv, out);
    k_stats_partial<<<256, 256, 0, stream>>>(out, edge_index, batch, ws);
    k_stats_final<<<1, 64, 0, stream>>>(ws);
    k_edge_final<<<256, 256, 0, stream>>>(out, ws, edge_attr, edge_index,
        batch, ln_w_s, ln_b_s, ln_w_v, w_skip, w_edge_s, b_edge_s, w_edge_v);
}